// Round 1
// baseline (783.631 us; speedup 1.0000x reference)
//
#include <hip/hip_runtime.h>
#include <math.h>

#define N_NODES 100000
#define N_EDGES 1600000
#define DIM 128
#define SCAN_BLK 2048
#define NBLK ((N_NODES + SCAN_BLK - 1) / SCAN_BLK)  // 49

// ---------------- CSR build ----------------

__global__ void hist_k(const int* __restrict__ row, int* __restrict__ deg) {
    int e = blockIdx.x * 256 + threadIdx.x;
    if (e < N_EDGES) atomicAdd(&deg[row[e]], 1);
}

// exclusive scan of deg[0..N) into offs[0..N); per-block totals into bsum
__global__ void scan1_k(const int* __restrict__ deg, int* __restrict__ offs,
                        int* __restrict__ bsum) {
    __shared__ int lds[256];
    int t = threadIdx.x;
    int base = blockIdx.x * SCAN_BLK + t * 8;
    int v[8];
    int s = 0;
#pragma unroll
    for (int i = 0; i < 8; i++) {
        int idx = base + i;
        int d = (idx < N_NODES) ? deg[idx] : 0;
        v[i] = s;
        s += d;
    }
    lds[t] = s;
    __syncthreads();
    for (int off = 1; off < 256; off <<= 1) {
        int add = (t >= off) ? lds[t - off] : 0;
        __syncthreads();
        lds[t] += add;
        __syncthreads();
    }
    int incl = lds[t];
    int excl = incl - s;
    if (t == 255) bsum[blockIdx.x] = incl;
#pragma unroll
    for (int i = 0; i < 8; i++) {
        int idx = base + i;
        if (idx < N_NODES) offs[idx] = excl + v[i];
    }
}

__global__ void scan2_k(int* __restrict__ bsum) {
    if (threadIdx.x == 0 && blockIdx.x == 0) {
        int run = 0;
        for (int b = 0; b < NBLK; b++) {
            int t = bsum[b];
            bsum[b] = run;
            run += t;
        }
    }
}

__global__ void scan3_k(int* __restrict__ offs, const int* __restrict__ bsum) {
    int i = blockIdx.x * 256 + threadIdx.x;
    if (i < N_NODES) offs[i] += bsum[i >> 11];  // 2048 = 2^11
}

__global__ void scatter_k(const int* __restrict__ row, const int* __restrict__ col,
                          const int* __restrict__ offs, int* __restrict__ cur,
                          int* __restrict__ scol) {
    int e = blockIdx.x * 256 + threadIdx.x;
    if (e < N_EDGES) {
        int r = row[e];
        int p = offs[r] + atomicAdd(&cur[r], 1);
        scol[p] = col[e];
    }
}

// ---------------- pass A: x_agg[n] = sum over in-edges of x[col_e] ----------------
// one 32-lane group per node, float4 per lane (128 feats)

__global__ __launch_bounds__(256) void xagg_k(const float* __restrict__ x,
                                              const int* __restrict__ offs,
                                              const int* __restrict__ deg,
                                              const int* __restrict__ scol,
                                              float* __restrict__ xagg) {
    int g = (blockIdx.x * 256 + threadIdx.x) >> 5;  // node id (grid exact)
    int lane = threadIdx.x & 31;
    int s = offs[g], d = deg[g];
    const float4* x4 = (const float4*)x;
    float ax = 0.f, ay = 0.f, az = 0.f, aw = 0.f;
    for (int i = 0; i < d; i++) {
        int c = scol[s + i];
        float4 v = x4[(size_t)c * 32 + lane];
        ax += v.x; ay += v.y; az += v.z; aw += v.w;
    }
    float4 o = {ax, ay, az, aw};
    ((float4*)xagg)[(size_t)g * 32 + lane] = o;
}

// ---------------- fused GEMMs ----------------
// k_act = lrelu(x@Wk); h_proj = x@Wl + b; q_agg = x_agg@Wq (in-place over x_agg)

__global__ __launch_bounds__(256) void gemm_k(
    const float* __restrict__ x, const float* __restrict__ xagg,
    const float* __restrict__ Wq, const float* __restrict__ Wk,
    const float* __restrict__ Wl, const float* __restrict__ bl,
    float* __restrict__ qagg, float* __restrict__ ka, float* __restrict__ hp) {
    __shared__ float xs[64 * 128];  // 32 KB x-tile
    __shared__ float ws[32 * 128];  // 16 KB W-slice
    int t = threadIdx.x;
    int row_base = blockIdx.x * 64;
    int tc = t & 31;   // 4 cols: 4*tc..4*tc+3
    int tr = t >> 5;   // 8 rows: tr*8..tr*8+7
    float4* xs4 = (float4*)xs;
    float4* ws4 = (float4*)ws;
    float4 b4 = ((const float4*)bl)[tc];

    for (int w = 0; w < 3; w++) {
        if (w == 0 || w == 2) {  // stage x tile (w=0) or x_agg tile (w=2)
            __syncthreads();
            const float4* src4 = (const float4*)((w == 0) ? x : xagg);
            for (int i = t; i < 64 * 32; i += 256) {
                int gi = row_base * 32 + i;
                float4 v = {0.f, 0.f, 0.f, 0.f};
                if (gi < N_NODES * 32) v = src4[gi];
                xs4[i] = v;
            }
        }
        const float4* W4 = (const float4*)((w == 0) ? Wk : (w == 1) ? Wl : Wq);
        float4 acc[8];
#pragma unroll
        for (int i = 0; i < 8; i++) acc[i] = make_float4(0.f, 0.f, 0.f, 0.f);
        for (int ks = 0; ks < 128; ks += 32) {
            __syncthreads();
            for (int i = t; i < 32 * 32; i += 256) ws4[i] = W4[ks * 32 + i];
            __syncthreads();
#pragma unroll 8
            for (int kk = 0; kk < 32; kk++) {
                float4 wv = ws4[kk * 32 + tc];
#pragma unroll
                for (int i = 0; i < 8; i++) {
                    float xv = xs[(tr * 8 + i) * 128 + ks + kk];
                    acc[i].x += xv * wv.x;
                    acc[i].y += xv * wv.y;
                    acc[i].z += xv * wv.z;
                    acc[i].w += xv * wv.w;
                }
            }
        }
        float* dst = (w == 0) ? ka : (w == 1) ? hp : qagg;
#pragma unroll
        for (int i = 0; i < 8; i++) {
            int r = row_base + tr * 8 + i;
            if (r < N_NODES) {
                float4 v = acc[i];
                if (w == 0) {  // leaky_relu for k_act
                    v.x = v.x > 0.f ? v.x : 0.2f * v.x;
                    v.y = v.y > 0.f ? v.y : 0.2f * v.y;
                    v.z = v.z > 0.f ? v.z : 0.2f * v.z;
                    v.w = v.w > 0.f ? v.w : 0.2f * v.w;
                } else if (w == 1) {  // + bias for h_proj
                    v.x += b4.x; v.y += b4.y; v.z += b4.z; v.w += b4.w;
                }
                ((float4*)dst)[(size_t)r * 32 + tc] = v;
            }
        }
    }
}

// ---------------- pass B: scores + online softmax + weighted aggregate ----------------
// one 32-lane group per destination node; k_act row held in regs (float4/lane)

__global__ __launch_bounds__(256) void attn_k(const float* __restrict__ kact,
                                              const float* __restrict__ qagg,
                                              const float* __restrict__ hproj,
                                              const int* __restrict__ offs,
                                              const int* __restrict__ deg,
                                              const int* __restrict__ scol,
                                              float* __restrict__ out) {
    int g = (blockIdx.x * 256 + threadIdx.x) >> 5;  // node id (grid exact)
    int lane = threadIdx.x & 31;
    int s = offs[g], d = deg[g];
    const float4* q4 = (const float4*)qagg;
    const float4* h4 = (const float4*)hproj;
    float4 kf = ((const float4*)kact)[(size_t)g * 32 + lane];
    const float scale = 0.08838834764831845f;  // 1/sqrt(128)

    float m = -INFINITY, S = 0.f;
    float ax = 0.f, ay = 0.f, az = 0.f, aw = 0.f;
    for (int i = 0; i < d; i++) {
        int c = scol[s + i];
        float4 q = q4[(size_t)c * 32 + lane];
        float part = kf.x * q.x + kf.y * q.y + kf.z * q.z + kf.w * q.w;
#pragma unroll
        for (int off = 16; off > 0; off >>= 1) part += __shfl_xor(part, off);
        float sc = part * scale;
        float4 h = h4[(size_t)c * 32 + lane];
        if (sc > m) {  // group-uniform branch (sc, m uniform across the 32 lanes)
            float corr = __expf(m - sc);  // exp(-inf)=0 on first edge
            S = S * corr + 1.f;
            ax = ax * corr + h.x; ay = ay * corr + h.y;
            az = az * corr + h.z; aw = aw * corr + h.w;
            m = sc;
        } else {
            float p = __expf(sc - m);
            S += p;
            ax += p * h.x; ay += p * h.y; az += p * h.z; aw += p * h.w;
        }
    }
    float inv = 1.f / (S + 1e-8f);  // d==0 -> acc==0 -> out 0, matches ref
    ax *= inv; ay *= inv; az *= inv; aw *= inv;
    ax = ax > 0.f ? ax : 0.2f * ax;
    ay = ay > 0.f ? ay : 0.2f * ay;
    az = az > 0.f ? az : 0.2f * az;
    aw = aw > 0.f ? aw : 0.2f * aw;
    float4 o = {ax, ay, az, aw};
    ((float4*)out)[(size_t)g * 32 + lane] = o;
}

// ---------------- launch ----------------

extern "C" void kernel_launch(void* const* d_in, const int* in_sizes, int n_in,
                              void* d_out, int out_size, void* d_ws, size_t ws_size,
                              hipStream_t stream) {
    const float* x  = (const float*)d_in[0];
    const int* row  = (const int*)d_in[1];              // edge_index[0]
    const int* col  = row + N_EDGES;                    // edge_index[1]
    const float* Wq = (const float*)d_in[2];
    const float* Wk = (const float*)d_in[3];
    // d_in[4] = W_v: unused by the reference's output
    const float* Wl = (const float*)d_in[5];
    const float* bl = (const float*)d_in[6];
    float* out = (float*)d_out;

    // workspace carve (~161 MB): buf0 (x_agg -> q_agg in place), k_act, h_proj, CSR
    float* buf0 = (float*)d_ws;                         // N*128 f32
    float* ka   = buf0 + (size_t)N_NODES * DIM;         // N*128 f32
    float* hp   = ka + (size_t)N_NODES * DIM;           // N*128 f32
    int* deg  = (int*)(hp + (size_t)N_NODES * DIM);     // N
    int* offs = deg + N_NODES;                          // N
    int* cur  = offs + N_NODES;                         // N
    int* bsum = cur + N_NODES;                          // 64
    int* scol = bsum + 64;                              // E

    hipMemsetAsync(deg, 0, N_NODES * sizeof(int), stream);
    hipMemsetAsync(cur, 0, N_NODES * sizeof(int), stream);

    hist_k<<<N_EDGES / 256, 256, 0, stream>>>(row, deg);
    scan1_k<<<NBLK, 256, 0, stream>>>(deg, offs, bsum);
    scan2_k<<<1, 64, 0, stream>>>(bsum);
    scan3_k<<<(N_NODES + 255) / 256, 256, 0, stream>>>(offs, bsum);
    scatter_k<<<N_EDGES / 256, 256, 0, stream>>>(row, col, offs, cur, scol);

    xagg_k<<<N_NODES / 8, 256, 0, stream>>>(x, offs, deg, scol, buf0);
    gemm_k<<<(N_NODES + 63) / 64, 256, 0, stream>>>(x, buf0, Wq, Wk, Wl, bl,
                                                    buf0, ka, hp);
    attn_k<<<N_NODES / 8, 256, 0, stream>>>(ka, buf0, hp, offs, deg, scol, out);
}

// Round 2
// 664.618 us; speedup vs baseline: 1.1791x; 1.1791x over previous
//
#include <hip/hip_runtime.h>
#include <math.h>

#define N_NODES 100000
#define N_EDGES 1600000
#define DIM 128
#define SCAN_BLK 2048
#define NBLK ((N_NODES + SCAN_BLK - 1) / SCAN_BLK)  // 49

// ---- bf16 helpers (RNE pack, cheap unpack) ----
static __device__ __forceinline__ unsigned bf16rne(float f) {
    unsigned u = __float_as_uint(f);
    return (u + 0x7FFFu + ((u >> 16) & 1u)) >> 16;
}
static __device__ __forceinline__ float bflo(unsigned u) { return __uint_as_float(u << 16); }
static __device__ __forceinline__ float bfhi(unsigned u) { return __uint_as_float(u & 0xFFFF0000u); }

// ---------------- CSR build ----------------

__global__ void hist_k(const int* __restrict__ row, int* __restrict__ deg) {
    int e = blockIdx.x * 256 + threadIdx.x;
    if (e < N_EDGES) atomicAdd(&deg[row[e]], 1);
}

__global__ void scan1_k(const int* __restrict__ deg, int* __restrict__ offs,
                        int* __restrict__ bsum) {
    __shared__ int lds[256];
    int t = threadIdx.x;
    int base = blockIdx.x * SCAN_BLK + t * 8;
    int v[8];
    int s = 0;
#pragma unroll
    for (int i = 0; i < 8; i++) {
        int idx = base + i;
        int d = (idx < N_NODES) ? deg[idx] : 0;
        v[i] = s;
        s += d;
    }
    lds[t] = s;
    __syncthreads();
    for (int off = 1; off < 256; off <<= 1) {
        int add = (t >= off) ? lds[t - off] : 0;
        __syncthreads();
        lds[t] += add;
        __syncthreads();
    }
    int incl = lds[t];
    int excl = incl - s;
    if (t == 255) bsum[blockIdx.x] = incl;
#pragma unroll
    for (int i = 0; i < 8; i++) {
        int idx = base + i;
        if (idx < N_NODES) offs[idx] = excl + v[i];
    }
}

__global__ void scan2_k(int* __restrict__ bsum) {
    if (threadIdx.x == 0 && blockIdx.x == 0) {
        int run = 0;
        for (int b = 0; b < NBLK; b++) {
            int t = bsum[b];
            bsum[b] = run;
            run += t;
        }
    }
}

__global__ void scan3_k(int* __restrict__ offs, const int* __restrict__ bsum) {
    int i = blockIdx.x * 256 + threadIdx.x;
    if (i < N_NODES) offs[i] += bsum[i >> 11];
}

__global__ void scatter_k(const int* __restrict__ row, const int* __restrict__ col,
                          const int* __restrict__ offs, int* __restrict__ cur,
                          int* __restrict__ scol) {
    int e = blockIdx.x * 256 + threadIdx.x;
    if (e < N_EDGES) {
        int r = row[e];
        int p = offs[r] + atomicAdd(&cur[r], 1);
        scol[p] = col[e];
    }
}

// ---------------- cast x -> bf16 ----------------
// grid exact: 12.8M elems / 8 per thread / 256 = 6250 blocks

__global__ void cast_k(const float4* __restrict__ x4, uint4* __restrict__ xb4) {
    int i = blockIdx.x * 256 + threadIdx.x;
    float4 a = x4[i * 2];
    float4 b = x4[i * 2 + 1];
    uint4 o;
    o.x = bf16rne(a.x) | (bf16rne(a.y) << 16);
    o.y = bf16rne(a.z) | (bf16rne(a.w) << 16);
    o.z = bf16rne(b.x) | (bf16rne(b.y) << 16);
    o.w = bf16rne(b.z) | (bf16rne(b.w) << 16);
    xb4[i] = o;
}

// ---------------- pass A: x_agg (bf16 in, bf16 out) ----------------
// 32-lane group per node; lane holds 4 feature slots (uint2 = 4 bf16)

__global__ __launch_bounds__(256) void xagg_k(const uint2* __restrict__ xb,
                                              const int* __restrict__ offs,
                                              const int* __restrict__ deg,
                                              const int* __restrict__ scol,
                                              uint2* __restrict__ xaggb) {
    int g = (blockIdx.x * 256 + threadIdx.x) >> 5;  // node id (grid exact)
    int lane = threadIdx.x & 31;
    int s = offs[g], d = deg[g];
    float a0 = 0.f, a1 = 0.f, a2 = 0.f, a3 = 0.f;
    for (int j = 0; j < d; j += 32) {
        int cb = (j + lane < d) ? scol[s + j + lane] : 0;
        int lim = min(32, d - j);
        for (int k = 0; k < lim; k++) {
            int c = __shfl(cb, k, 32);
            uint2 u = xb[(size_t)c * 32 + lane];
            a0 += bflo(u.x); a1 += bfhi(u.x);
            a2 += bflo(u.y); a3 += bfhi(u.y);
        }
    }
    uint2 o;
    o.x = bf16rne(a0) | (bf16rne(a1) << 16);
    o.y = bf16rne(a2) | (bf16rne(a3) << 16);
    xaggb[(size_t)g * 32 + lane] = o;
}

// ---------------- GEMMs: kact_b = bf16(lrelu(x@Wk)); qagg_b = bf16(xaggb@Wq) ----------------
// qaggb aliases xaggb (in-place; tile staged to LDS before any write)

__global__ __launch_bounds__(256) void gemm_k(
    const float* __restrict__ x, const uint2* xaggb,
    const float* __restrict__ Wk, const float* __restrict__ Wq,
    uint2* __restrict__ kactb, uint2* qaggb) {
    __shared__ float xs[64 * 128];  // 32 KB
    __shared__ float ws[32 * 128];  // 16 KB
    int t = threadIdx.x;
    int row_base = blockIdx.x * 64;
    int tc = t & 31;   // 4 cols
    int tr = t >> 5;   // 8 rows
    float4* xs4 = (float4*)xs;
    float4* ws4 = (float4*)ws;

    for (int w = 0; w < 2; w++) {
        __syncthreads();
        if (w == 0) {
            const float4* src4 = (const float4*)x;
            for (int i = t; i < 64 * 32; i += 256) {
                int gi = row_base * 32 + i;
                float4 v = {0.f, 0.f, 0.f, 0.f};
                if (gi < N_NODES * 32) v = src4[gi];
                xs4[i] = v;
            }
        } else {
            for (int i = t; i < 64 * 32; i += 256) {
                int r = row_base + (i >> 5);
                uint2 u = {0u, 0u};
                if (r < N_NODES) u = xaggb[(size_t)r * 32 + (i & 31)];
                float4 v = {bflo(u.x), bfhi(u.x), bflo(u.y), bfhi(u.y)};
                xs4[i] = v;
            }
        }
        const float4* W4 = (const float4*)((w == 0) ? Wk : Wq);
        float4 acc[8];
#pragma unroll
        for (int i = 0; i < 8; i++) acc[i] = make_float4(0.f, 0.f, 0.f, 0.f);
        for (int ks = 0; ks < 128; ks += 32) {
            __syncthreads();
            for (int i = t; i < 32 * 32; i += 256) ws4[i] = W4[ks * 32 + i];
            __syncthreads();
#pragma unroll 8
            for (int kk = 0; kk < 32; kk++) {
                float4 wv = ws4[kk * 32 + tc];
#pragma unroll
                for (int i = 0; i < 8; i++) {
                    float xv = xs[(tr * 8 + i) * 128 + ks + kk];
                    acc[i].x += xv * wv.x;
                    acc[i].y += xv * wv.y;
                    acc[i].z += xv * wv.z;
                    acc[i].w += xv * wv.w;
                }
            }
        }
        uint2* dst = (w == 0) ? kactb : qaggb;
#pragma unroll
        for (int i = 0; i < 8; i++) {
            int r = row_base + tr * 8 + i;
            if (r < N_NODES) {
                float4 v = acc[i];
                if (w == 0) {  // leaky_relu for k_act
                    v.x = v.x > 0.f ? v.x : 0.2f * v.x;
                    v.y = v.y > 0.f ? v.y : 0.2f * v.y;
                    v.z = v.z > 0.f ? v.z : 0.2f * v.z;
                    v.w = v.w > 0.f ? v.w : 0.2f * v.w;
                }
                uint2 o;
                o.x = bf16rne(v.x) | (bf16rne(v.y) << 16);
                o.y = bf16rne(v.z) | (bf16rne(v.w) << 16);
                dst[(size_t)r * 32 + tc] = o;
            }
        }
    }
}

// ---------------- pass B: scores + online softmax + alpha-weighted x aggregate ----------------

__global__ __launch_bounds__(256) void attn_k(const uint2* __restrict__ kactb,
                                              const uint2* __restrict__ qaggb,
                                              const uint2* __restrict__ xb,
                                              const int* __restrict__ offs,
                                              const int* __restrict__ deg,
                                              const int* __restrict__ scol,
                                              float* __restrict__ xw,
                                              float* __restrict__ sumw) {
    int g = (blockIdx.x * 256 + threadIdx.x) >> 5;  // node id (grid exact)
    int lane = threadIdx.x & 31;
    int s = offs[g], d = deg[g];
    uint2 ku = kactb[(size_t)g * 32 + lane];
    float k0 = bflo(ku.x), k1 = bfhi(ku.x), k2 = bflo(ku.y), k3 = bfhi(ku.y);
    const float scale = 0.08838834764831845f;  // 1/sqrt(128)

    float m = -INFINITY, S = 0.f;
    float a0 = 0.f, a1 = 0.f, a2 = 0.f, a3 = 0.f;
    for (int j = 0; j < d; j += 32) {
        int cb = (j + lane < d) ? scol[s + j + lane] : 0;
        int lim = min(32, d - j);
        for (int k = 0; k < lim; k++) {
            int c = __shfl(cb, k, 32);
            uint2 qu = qaggb[(size_t)c * 32 + lane];
            uint2 xu = xb[(size_t)c * 32 + lane];
            float part = k0 * bflo(qu.x) + k1 * bfhi(qu.x)
                       + k2 * bflo(qu.y) + k3 * bfhi(qu.y);
#pragma unroll
            for (int off = 16; off > 0; off >>= 1) part += __shfl_xor(part, off);
            float sc = part * scale;
            float x0 = bflo(xu.x), x1 = bfhi(xu.x), x2 = bflo(xu.y), x3 = bfhi(xu.y);
            if (sc > m) {  // group-uniform branch
                float corr = __expf(m - sc);  // exp(-inf)=0 on first edge
                S = S * corr + 1.f;
                a0 = a0 * corr + x0; a1 = a1 * corr + x1;
                a2 = a2 * corr + x2; a3 = a3 * corr + x3;
                m = sc;
            } else {
                float p = __expf(sc - m);
                S += p;
                a0 += p * x0; a1 += p * x1; a2 += p * x2; a3 += p * x3;
            }
        }
    }
    float inv = 1.f / (S + 1e-8f);
    float4 o = {a0 * inv, a1 * inv, a2 * inv, a3 * inv};
    ((float4*)xw)[(size_t)g * 32 + lane] = o;
    if (lane == 0) sumw[g] = S * inv;  // Σ alpha (for exact bias term)
}

// ---------------- final: out = lrelu(xw @ Wl + sumw*b) ----------------

__global__ __launch_bounds__(256) void fin_k(const float* __restrict__ xw,
                                             const float* __restrict__ Wl,
                                             const float* __restrict__ bl,
                                             const float* __restrict__ sumw,
                                             float* __restrict__ out) {
    __shared__ float xs[64 * 128];
    __shared__ float ws[32 * 128];
    __shared__ float sw[64];
    int t = threadIdx.x;
    int row_base = blockIdx.x * 64;
    int tc = t & 31;
    int tr = t >> 5;
    float4* xs4 = (float4*)xs;
    float4* ws4 = (float4*)ws;
    const float4* src4 = (const float4*)xw;
    for (int i = t; i < 64 * 32; i += 256) {
        int gi = row_base * 32 + i;
        float4 v = {0.f, 0.f, 0.f, 0.f};
        if (gi < N_NODES * 32) v = src4[gi];
        xs4[i] = v;
    }
    if (t < 64) sw[t] = (row_base + t < N_NODES) ? sumw[row_base + t] : 0.f;
    float4 b4 = ((const float4*)bl)[tc];
    const float4* W4 = (const float4*)Wl;
    float4 acc[8];
#pragma unroll
    for (int i = 0; i < 8; i++) acc[i] = make_float4(0.f, 0.f, 0.f, 0.f);
    for (int ks = 0; ks < 128; ks += 32) {
        __syncthreads();
        for (int i = t; i < 32 * 32; i += 256) ws4[i] = W4[ks * 32 + i];
        __syncthreads();
#pragma unroll 8
        for (int kk = 0; kk < 32; kk++) {
            float4 wv = ws4[kk * 32 + tc];
#pragma unroll
            for (int i = 0; i < 8; i++) {
                float xv = xs[(tr * 8 + i) * 128 + ks + kk];
                acc[i].x += xv * wv.x;
                acc[i].y += xv * wv.y;
                acc[i].z += xv * wv.z;
                acc[i].w += xv * wv.w;
            }
        }
    }
#pragma unroll
    for (int i = 0; i < 8; i++) {
        int r = row_base + tr * 8 + i;
        if (r < N_NODES) {
            float swv = sw[tr * 8 + i];
            float4 v = acc[i];
            v.x += swv * b4.x; v.y += swv * b4.y;
            v.z += swv * b4.z; v.w += swv * b4.w;
            v.x = v.x > 0.f ? v.x : 0.2f * v.x;
            v.y = v.y > 0.f ? v.y : 0.2f * v.y;
            v.z = v.z > 0.f ? v.z : 0.2f * v.z;
            v.w = v.w > 0.f ? v.w : 0.2f * v.w;
            ((float4*)out)[(size_t)r * 32 + tc] = v;
        }
    }
}

// ---------------- launch ----------------

extern "C" void kernel_launch(void* const* d_in, const int* in_sizes, int n_in,
                              void* d_out, int out_size, void* d_ws, size_t ws_size,
                              hipStream_t stream) {
    const float* x  = (const float*)d_in[0];
    const int* row  = (const int*)d_in[1];
    const int* col  = row + N_EDGES;
    const float* Wq = (const float*)d_in[2];
    const float* Wk = (const float*)d_in[3];
    // d_in[4] = W_v: unused
    const float* Wl = (const float*)d_in[5];
    const float* bl = (const float*)d_in[6];
    float* out = (float*)d_out;

    // workspace carve (~136 MB)
    float* xw    = (float*)d_ws;                        // N*128 f32 (51.2 MB)
    uint2* xb    = (uint2*)(xw + (size_t)N_NODES * DIM);// N*32 uint2 (25.6 MB)
    uint2* xaggb = xb + (size_t)N_NODES * 32;           // 25.6 MB (qaggb in-place)
    uint2* kactb = xaggb + (size_t)N_NODES * 32;        // 25.6 MB
    float* sumw  = (float*)(kactb + (size_t)N_NODES * 32);  // N f32
    int* deg  = (int*)(sumw + N_NODES);
    int* offs = deg + N_NODES;
    int* cur  = offs + N_NODES;
    int* bsum = cur + N_NODES;
    int* scol = bsum + 64;

    hipMemsetAsync(deg, 0, N_NODES * sizeof(int), stream);
    hipMemsetAsync(cur, 0, N_NODES * sizeof(int), stream);

    hist_k<<<N_EDGES / 256, 256, 0, stream>>>(row, deg);
    scan1_k<<<NBLK, 256, 0, stream>>>(deg, offs, bsum);
    scan2_k<<<1, 64, 0, stream>>>(bsum);
    scan3_k<<<(N_NODES + 255) / 256, 256, 0, stream>>>(offs, bsum);
    scatter_k<<<N_EDGES / 256, 256, 0, stream>>>(row, col, offs, cur, scol);

    cast_k<<<(N_NODES * DIM / 8) / 256, 256, 0, stream>>>((const float4*)x, (uint4*)xb);
    xagg_k<<<N_NODES / 8, 256, 0, stream>>>(xb, offs, deg, scol, xaggb);
    gemm_k<<<(N_NODES + 63) / 64, 256, 0, stream>>>(x, xaggb, Wk, Wq, kactb, xaggb);
    attn_k<<<N_NODES / 8, 256, 0, stream>>>(kactb, xaggb, xb, offs, deg, scol, xw, sumw);
    fin_k<<<(N_NODES + 63) / 64, 256, 0, stream>>>(xw, Wl, bl, sumw, out);
}

// Round 3
// 589.910 us; speedup vs baseline: 1.3284x; 1.1266x over previous
//
#include <hip/hip_runtime.h>
#include <math.h>

#define N_NODES 100000
#define N_EDGES 1600000
#define DIM 128
#define SCAN_BLK 2048
#define NBLK ((N_NODES + SCAN_BLK - 1) / SCAN_BLK)  // 49

typedef short bf16x8 __attribute__((ext_vector_type(8)));
typedef float f32x4 __attribute__((ext_vector_type(4)));

// ---- bf16 helpers (RNE pack, cheap unpack) ----
static __device__ __forceinline__ unsigned bf16rne(float f) {
    unsigned u = __float_as_uint(f);
    return (u + 0x7FFFu + ((u >> 16) & 1u)) >> 16;
}
static __device__ __forceinline__ float bflo(unsigned u) { return __uint_as_float(u << 16); }
static __device__ __forceinline__ float bfhi(unsigned u) { return __uint_as_float(u & 0xFFFF0000u); }

// ---------------- CSR build ----------------

__global__ void hist_k(const int* __restrict__ row, int* __restrict__ deg) {
    int e = blockIdx.x * 256 + threadIdx.x;
    if (e < N_EDGES) atomicAdd(&deg[row[e]], 1);
}

__global__ void scan1_k(const int* __restrict__ deg, int* __restrict__ offs,
                        int* __restrict__ bsum) {
    __shared__ int lds[256];
    int t = threadIdx.x;
    int base = blockIdx.x * SCAN_BLK + t * 8;
    int v[8];
    int s = 0;
#pragma unroll
    for (int i = 0; i < 8; i++) {
        int idx = base + i;
        int d = (idx < N_NODES) ? deg[idx] : 0;
        v[i] = s;
        s += d;
    }
    lds[t] = s;
    __syncthreads();
    for (int off = 1; off < 256; off <<= 1) {
        int add = (t >= off) ? lds[t - off] : 0;
        __syncthreads();
        lds[t] += add;
        __syncthreads();
    }
    int incl = lds[t];
    int excl = incl - s;
    if (t == 255) bsum[blockIdx.x] = incl;
#pragma unroll
    for (int i = 0; i < 8; i++) {
        int idx = base + i;
        if (idx < N_NODES) offs[idx] = excl + v[i];
    }
}

__global__ void scan2_k(int* __restrict__ bsum) {
    if (threadIdx.x == 0 && blockIdx.x == 0) {
        int run = 0;
        for (int b = 0; b < NBLK; b++) {
            int t = bsum[b];
            bsum[b] = run;
            run += t;
        }
    }
}

__global__ void scan3_k(int* __restrict__ offs, const int* __restrict__ bsum) {
    int i = blockIdx.x * 256 + threadIdx.x;
    if (i < N_NODES) offs[i] += bsum[i >> 11];
}

__global__ void scatter_k(const int* __restrict__ row, const int* __restrict__ col,
                          const int* __restrict__ offs, int* __restrict__ cur,
                          int* __restrict__ scol) {
    int e = blockIdx.x * 256 + threadIdx.x;
    if (e < N_EDGES) {
        int r = row[e];
        int p = offs[r] + atomicAdd(&cur[r], 1);
        scol[p] = col[e];
    }
}

// ---------------- cast x -> bf16 ----------------

__global__ void cast_k(const float4* __restrict__ x4, uint4* __restrict__ xb4) {
    int i = blockIdx.x * 256 + threadIdx.x;
    float4 a = x4[i * 2];
    float4 b = x4[i * 2 + 1];
    uint4 o;
    o.x = bf16rne(a.x) | (bf16rne(a.y) << 16);
    o.y = bf16rne(a.z) | (bf16rne(a.w) << 16);
    o.z = bf16rne(b.x) | (bf16rne(b.y) << 16);
    o.w = bf16rne(b.z) | (bf16rne(b.w) << 16);
    xb4[i] = o;
}

// ---------------- W prep: transpose + split into bf16 hi/lo ----------------
// WT layout: [n][k] bf16 (B-fragment loads become contiguous 16B)

__global__ void wprep_k(const float* __restrict__ Wq, const float* __restrict__ Wk,
                        const float* __restrict__ Wl,
                        ushort* __restrict__ Th0, ushort* __restrict__ Tl0,
                        ushort* __restrict__ Th1, ushort* __restrict__ Tl1,
                        ushort* __restrict__ Th2, ushort* __restrict__ Tl2) {
    int i = blockIdx.x * 256 + threadIdx.x;  // 0..49151
    int w = i >> 14, e = i & 16383;
    int k = e >> 7, n = e & 127;
    const float* W = (w == 0) ? Wq : (w == 1) ? Wk : Wl;
    float v = W[e];
    unsigned hi = bf16rne(v);
    float lo = v - bflo(hi);
    unsigned lb = bf16rne(lo);
    ushort* Th = (w == 0) ? Th0 : (w == 1) ? Th1 : Th2;
    ushort* Tl = (w == 0) ? Tl0 : (w == 1) ? Tl1 : Tl2;
    Th[n * 128 + k] = (ushort)hi;
    Tl[n * 128 + k] = (ushort)lb;
}

// ---------------- pass A: x_agg (bf16 in, bf16 out) ----------------

__global__ __launch_bounds__(256) void xagg_k(const uint2* __restrict__ xb,
                                              const int* __restrict__ offs,
                                              const int* __restrict__ deg,
                                              const int* __restrict__ scol,
                                              uint2* __restrict__ xaggb) {
    int g = (blockIdx.x * 256 + threadIdx.x) >> 5;
    int lane = threadIdx.x & 31;
    int s = offs[g], d = deg[g];
    float a0 = 0.f, a1 = 0.f, a2 = 0.f, a3 = 0.f;
    for (int j = 0; j < d; j += 32) {
        int cb = (j + lane < d) ? scol[s + j + lane] : 0;
        int lim = min(32, d - j);
        for (int k = 0; k < lim; k++) {
            int c = __shfl(cb, k, 32);
            uint2 u = xb[(size_t)c * 32 + lane];
            a0 += bflo(u.x); a1 += bfhi(u.x);
            a2 += bflo(u.y); a3 += bfhi(u.y);
        }
    }
    uint2 o;
    o.x = bf16rne(a0) | (bf16rne(a1) << 16);
    o.y = bf16rne(a2) | (bf16rne(a3) << 16);
    xaggb[(size_t)g * 32 + lane] = o;
}

// ---------------- MFMA GEMM: D = bf16( [lrelu]( A @ (Whi+Wlo) ) ) ----------------
// A: [N][128] bf16 row-major. WT: [n][k] bf16. Block=256 (4 waves), 128 rows/block,
// wave = 32 rows x 128 cols = 2 rowtiles x 8 coltiles of 16x16x32 MFMA. No LDS.

__global__ __launch_bounds__(256) void mgemm_k(const ushort* __restrict__ Ab,
                                               const ushort* __restrict__ BTh,
                                               const ushort* __restrict__ BTl,
                                               ushort* __restrict__ Db,
                                               int do_lrelu) {
    int tid = threadIdx.x;
    int wave = tid >> 6, lane = tid & 63;
    int ln15 = lane & 15, quad = (lane >> 4) & 3;
    long base = (long)blockIdx.x * 128 + wave * 32;

    const bf16x8* A8 = (const bf16x8*)Ab;     // 16 frags per row
    const bf16x8* Bh8 = (const bf16x8*)BTh;
    const bf16x8* Bl8 = (const bf16x8*)BTl;

    bf16x8 Af[2][4];
#pragma unroll
    for (int r = 0; r < 2; r++) {
        long row = base + r * 16 + ln15;
#pragma unroll
        for (int s = 0; s < 4; s++) Af[r][s] = A8[row * 16 + s * 4 + quad];
    }
    f32x4 acc[2][8];
#pragma unroll
    for (int r = 0; r < 2; r++)
#pragma unroll
        for (int t = 0; t < 8; t++) acc[r][t] = (f32x4){0.f, 0.f, 0.f, 0.f};

#pragma unroll
    for (int phase = 0; phase < 2; phase++) {
        const bf16x8* B8 = phase ? Bl8 : Bh8;
#pragma unroll
        for (int s = 0; s < 4; s++) {
#pragma unroll
            for (int t = 0; t < 8; t++) {
                bf16x8 b = B8[(t * 16 + ln15) * 16 + s * 4 + quad];
                acc[0][t] = __builtin_amdgcn_mfma_f32_16x16x32_bf16(Af[0][s], b, acc[0][t], 0, 0, 0);
                acc[1][t] = __builtin_amdgcn_mfma_f32_16x16x32_bf16(Af[1][s], b, acc[1][t], 0, 0, 0);
            }
        }
    }
    // D layout: col = ln15 (within tile), row = quad*4 + reg
#pragma unroll
    for (int r = 0; r < 2; r++) {
#pragma unroll
        for (int reg = 0; reg < 4; reg++) {
            long node = base + r * 16 + quad * 4 + reg;
            if (node < N_NODES) {
#pragma unroll
                for (int t = 0; t < 8; t++) {
                    float v = acc[r][t][reg];
                    if (do_lrelu) v = v > 0.f ? v : 0.2f * v;
                    Db[node * 128 + t * 16 + ln15] = (ushort)bf16rne(v);
                }
            }
        }
    }
}

// ---------------- pass B: online-softmax attention, bf16 xw out ----------------

__global__ __launch_bounds__(256) void attn_k(const uint2* __restrict__ kactb,
                                              const uint2* __restrict__ qaggb,
                                              const uint2* __restrict__ xb,
                                              const int* __restrict__ offs,
                                              const int* __restrict__ deg,
                                              const int* __restrict__ scol,
                                              uint2* __restrict__ xwb,
                                              float* __restrict__ sumw) {
    int g = (blockIdx.x * 256 + threadIdx.x) >> 5;
    int lane = threadIdx.x & 31;
    int s = offs[g], d = deg[g];
    uint2 ku = kactb[(size_t)g * 32 + lane];
    float k0 = bflo(ku.x), k1 = bfhi(ku.x), k2 = bflo(ku.y), k3 = bfhi(ku.y);
    const float scale = 0.08838834764831845f;  // 1/sqrt(128)

    float m = -INFINITY, S = 0.f;
    float a0 = 0.f, a1 = 0.f, a2 = 0.f, a3 = 0.f;
    for (int j = 0; j < d; j += 32) {
        int cb = (j + lane < d) ? scol[s + j + lane] : 0;
        int lim = min(32, d - j);
        for (int k = 0; k < lim; k++) {
            int c = __shfl(cb, k, 32);
            uint2 qu = qaggb[(size_t)c * 32 + lane];
            uint2 xu = xb[(size_t)c * 32 + lane];
            float part = k0 * bflo(qu.x) + k1 * bfhi(qu.x)
                       + k2 * bflo(qu.y) + k3 * bfhi(qu.y);
#pragma unroll
            for (int off = 16; off > 0; off >>= 1) part += __shfl_xor(part, off);
            float sc = part * scale;
            float x0 = bflo(xu.x), x1 = bfhi(xu.x), x2 = bflo(xu.y), x3 = bfhi(xu.y);
            if (sc > m) {  // group-uniform branch
                float corr = __expf(m - sc);
                S = S * corr + 1.f;
                a0 = a0 * corr + x0; a1 = a1 * corr + x1;
                a2 = a2 * corr + x2; a3 = a3 * corr + x3;
                m = sc;
            } else {
                float p = __expf(sc - m);
                S += p;
                a0 += p * x0; a1 += p * x1; a2 += p * x2; a3 += p * x3;
            }
        }
    }
    float inv = 1.f / (S + 1e-8f);
    uint2 o;
    o.x = bf16rne(a0 * inv) | (bf16rne(a1 * inv) << 16);
    o.y = bf16rne(a2 * inv) | (bf16rne(a3 * inv) << 16);
    xwb[(size_t)g * 32 + lane] = o;
    if (lane == 0) sumw[g] = S * inv;  // Σ alpha (for exact bias term)
}

// ---------------- final MFMA GEMM: out = lrelu(xw @ Wl + sumw*b), f32 out ----------------

__global__ __launch_bounds__(256) void fin_k(const ushort* __restrict__ Ab,
                                             const ushort* __restrict__ BTh,
                                             const ushort* __restrict__ BTl,
                                             const float* __restrict__ bl,
                                             const float* __restrict__ sumw,
                                             float* __restrict__ out) {
    int tid = threadIdx.x;
    int wave = tid >> 6, lane = tid & 63;
    int ln15 = lane & 15, quad = (lane >> 4) & 3;
    long base = (long)blockIdx.x * 128 + wave * 32;

    const bf16x8* A8 = (const bf16x8*)Ab;
    const bf16x8* Bh8 = (const bf16x8*)BTh;
    const bf16x8* Bl8 = (const bf16x8*)BTl;

    bf16x8 Af[2][4];
#pragma unroll
    for (int r = 0; r < 2; r++) {
        long row = base + r * 16 + ln15;
#pragma unroll
        for (int s = 0; s < 4; s++) Af[r][s] = A8[row * 16 + s * 4 + quad];
    }
    float blv[8];
#pragma unroll
    for (int t = 0; t < 8; t++) blv[t] = bl[t * 16 + ln15];

    f32x4 acc[2][8];
#pragma unroll
    for (int r = 0; r < 2; r++)
#pragma unroll
        for (int t = 0; t < 8; t++) acc[r][t] = (f32x4){0.f, 0.f, 0.f, 0.f};

#pragma unroll
    for (int phase = 0; phase < 2; phase++) {
        const bf16x8* B8 = phase ? Bl8 : Bh8;
#pragma unroll
        for (int s = 0; s < 4; s++) {
#pragma unroll
            for (int t = 0; t < 8; t++) {
                bf16x8 b = B8[(t * 16 + ln15) * 16 + s * 4 + quad];
                acc[0][t] = __builtin_amdgcn_mfma_f32_16x16x32_bf16(Af[0][s], b, acc[0][t], 0, 0, 0);
                acc[1][t] = __builtin_amdgcn_mfma_f32_16x16x32_bf16(Af[1][s], b, acc[1][t], 0, 0, 0);
            }
        }
    }
#pragma unroll
    for (int r = 0; r < 2; r++) {
#pragma unroll
        for (int reg = 0; reg < 4; reg++) {
            long node = base + r * 16 + quad * 4 + reg;
            if (node < N_NODES) {
                float sw = sumw[node];
#pragma unroll
                for (int t = 0; t < 8; t++) {
                    float v = acc[r][t][reg] + sw * blv[t];
                    v = v > 0.f ? v : 0.2f * v;
                    out[node * 128 + t * 16 + ln15] = v;
                }
            }
        }
    }
}

// ---------------- launch ----------------

extern "C" void kernel_launch(void* const* d_in, const int* in_sizes, int n_in,
                              void* d_out, int out_size, void* d_ws, size_t ws_size,
                              hipStream_t stream) {
    const float* x  = (const float*)d_in[0];
    const int* row  = (const int*)d_in[1];
    const int* col  = row + N_EDGES;
    const float* Wq = (const float*)d_in[2];
    const float* Wk = (const float*)d_in[3];
    // d_in[4] = W_v: unused
    const float* Wl = (const float*)d_in[5];
    const float* bl = (const float*)d_in[6];
    float* out = (float*)d_out;

    // workspace carve (~110 MB). Order matters: MFMA A-loads overread <=96 rows
    // past each array; every bf16 node-array has a valid neighbor after it.
    ushort* xwb   = (ushort*)d_ws;                       // N*128 bf16 (25.6 MB)
    ushort* xb    = xwb + (size_t)N_NODES * DIM;         // 25.6 MB
    ushort* xaggb = xb + (size_t)N_NODES * DIM;          // 25.6 MB (qagg in-place)
    ushort* kactb = xaggb + (size_t)N_NODES * DIM;       // 25.6 MB
    ushort* wbuf  = kactb + (size_t)N_NODES * DIM;       // 6*16384 bf16 (192 KB)
    ushort* WqTh = wbuf, *WqTl = wbuf + 16384;
    ushort* WkTh = wbuf + 2 * 16384, *WkTl = wbuf + 3 * 16384;
    ushort* WlTh = wbuf + 4 * 16384, *WlTl = wbuf + 5 * 16384;
    float* sumw = (float*)(wbuf + 6 * 16384);            // N f32
    int* deg  = (int*)(sumw + N_NODES);
    int* offs = deg + N_NODES;
    int* cur  = offs + N_NODES;
    int* bsum = cur + N_NODES;
    int* scol = bsum + 64;                               // E

    hipMemsetAsync(deg, 0, N_NODES * sizeof(int), stream);
    hipMemsetAsync(cur, 0, N_NODES * sizeof(int), stream);

    hist_k<<<N_EDGES / 256, 256, 0, stream>>>(row, deg);
    scan1_k<<<NBLK, 256, 0, stream>>>(deg, offs, bsum);
    scan2_k<<<1, 64, 0, stream>>>(bsum);
    scan3_k<<<(N_NODES + 255) / 256, 256, 0, stream>>>(offs, bsum);
    scatter_k<<<N_EDGES / 256, 256, 0, stream>>>(row, col, offs, cur, scol);

    cast_k<<<(N_NODES * DIM / 8) / 256, 256, 0, stream>>>((const float4*)x, (uint4*)xb);
    wprep_k<<<192, 256, 0, stream>>>(Wq, Wk, Wl, WqTh, WqTl, WkTh, WkTl, WlTh, WlTl);

    xagg_k<<<N_NODES / 8, 256, 0, stream>>>((const uint2*)xb, offs, deg, scol,
                                            (uint2*)xaggb);
    int gblk = (N_NODES + 127) / 128;  // 782
    mgemm_k<<<gblk, 256, 0, stream>>>(xb, WkTh, WkTl, kactb, 1);     // k_act
    mgemm_k<<<gblk, 256, 0, stream>>>(xaggb, WqTh, WqTl, xaggb, 0);  // q_agg in-place
    attn_k<<<N_NODES / 8, 256, 0, stream>>>((const uint2*)kactb, (const uint2*)xaggb,
                                            (const uint2*)xb, offs, deg, scol,
                                            (uint2*)xwb, sumw);
    fin_k<<<gblk, 256, 0, stream>>>(xwb, WlTh, WlTl, bl, sumw, out);
}